// Round 1
// baseline (289.421 us; speedup 1.0000x reference)
//
#include <hip/hip_runtime.h>

#define TPB 256
#define NPTS 2000
#define M1C 100
#define M2C 5
#define KNN 20
#define CANDCAP 128

// Bitwise-exact squared distance matching numpy/jax fp32 sequential sum:
// ((dx*dx + dy*dy) + dz*dz), no FMA contraction.
__device__ __forceinline__ float dist3(float px, float py, float pz,
                                       float qx, float qy, float qz) {
#pragma clang fp contract(off)
    float dx = px - qx;
    float dy = py - qy;
    float dz = pz - qz;
    return dx * dx + dy * dy + dz * dz;
}

// Wave-wide argmax with first-index tie-break; all 64 lanes receive result.
__device__ __forceinline__ void waveArgmax(float& v, int& idx) {
#pragma unroll
    for (int off = 32; off > 0; off >>= 1) {
        float ov = __shfl_xor(v, off);
        int oi = __shfl_xor(idx, off);
        if (ov > v || (ov == v && oi < idx)) { v = ov; idx = oi; }
    }
}

__global__ __launch_bounds__(TPB) void pointnet_kernel(
    const float* __restrict__ P,
    const float* __restrict__ W1, const float* __restrict__ b1,
    const float* __restrict__ W2, const float* __restrict__ b2,
    const float* __restrict__ W3, const float* __restrict__ b3,
    const float* __restrict__ D1, const float* __restrict__ bD1,
    const float* __restrict__ D2, const float* __restrict__ bD2,
    const float* __restrict__ D3, const float* __restrict__ bD3,
    float* __restrict__ out)
{
    __shared__ float sx[NPTS], sy[NPTS], sz[NPTS];
    __shared__ float smpx[M1C], smpy[M1C], smpz[M1C];
    __shared__ float s2x[M2C], s2y[M2C], s2z[M2C];
    __shared__ int   fps1[M1C];
    __shared__ int   fps2[M2C];
    __shared__ float f1s[M1C][5];
    __shared__ float f2s[M2C][25];
    __shared__ float latent[45];
    __shared__ float decv[M2C][3];
    __shared__ float cfs[M2C][25];
    __shared__ float dec2s[M1C][3];
    __shared__ float cf2s[M1C][5];
    __shared__ float w1s[15], b1s[5], w2s[200], b2s[25], w3s[1260], b3s[45];
    __shared__ float candd[4][CANDCAP];
    __shared__ int   candi[4][CANDCAP];
    __shared__ float rv[4];
    __shared__ int   ri[4];
    __shared__ int   bcast;

    const int b = blockIdx.x;
    const int tid = threadIdx.x;
    const int lane = tid & 63;
    const int wid = tid >> 6;

    // mask constants: must match f32(python_float r*r), computed in f64 then cast
    const float R1SQ = (float)(0.3 * 0.3);
    const float R2SQ = (float)(1.0 * 1.0);

    // ---- stage points (SoA) + small weights into LDS ----
    const float* Pb = P + (size_t)b * (NPTS * 3);
    for (int j = tid; j < NPTS; j += TPB) {
        sx[j] = Pb[3 * j + 0];
        sy[j] = Pb[3 * j + 1];
        sz[j] = Pb[3 * j + 2];
    }
    for (int t = tid; t < 15; t += TPB) w1s[t] = W1[t];
    for (int t = tid; t < 5; t += TPB) b1s[t] = b1[t];
    for (int t = tid; t < 200; t += TPB) w2s[t] = W2[t];
    for (int t = tid; t < 25; t += TPB) b2s[t] = b2[t];
    for (int t = tid; t < 1260; t += TPB) w3s[t] = W3[t];
    for (int t = tid; t < 45; t += TPB) b3s[t] = b3[t];
    __syncthreads();

    // ---- FPS1: 100 samples from 2000 points (sequential scan) ----
    float mind[8];
#pragma unroll
    for (int k = 0; k < 8; k++) mind[k] = 1e10f;
    int last = 0;
    for (int it = 0; it < M1C; ++it) {
        if (tid == 0) fps1[it] = last;
        float qx = sx[last], qy = sy[last], qz = sz[last];
        float bv = -1.0f;
        int bi = 0x7fffffff;
#pragma unroll
        for (int k = 0; k < 8; k++) {
            int j = tid + (k << 8);
            if (j < NPTS) {
                float d = dist3(sx[j], sy[j], sz[j], qx, qy, qz);
                float m = fminf(mind[k], d);
                mind[k] = m;
                if (m > bv) { bv = m; bi = j; }   // strict >: earliest j wins ties
            }
        }
        waveArgmax(bv, bi);
        if (lane == 0) { rv[wid] = bv; ri[wid] = bi; }
        __syncthreads();
        if (tid == 0) {
            float v = rv[0]; int x = ri[0];
            for (int w = 1; w < 4; w++) {
                if (rv[w] > v || (rv[w] == v && ri[w] < x)) { v = rv[w]; x = ri[w]; }
            }
            bcast = x;
        }
        __syncthreads();
        last = bcast;
    }

    // gather sampled coords
    for (int t = tid; t < M1C; t += TPB) {
        int j = fps1[t];
        smpx[t] = sx[j]; smpy[t] = sy[j]; smpz[t] = sz[j];
    }
    __syncthreads();

    // ---- knn1 + MLP1 -> f1 (one wave per sample, 4 waves) ----
    for (int s = wid; s < M1C; s += 4) {
        float qx = smpx[s], qy = smpy[s], qz = smpz[s];
        int cn = 0;
        for (int c = 0; c < 32; c++) {
            int j = c * 64 + lane;
            float d = 0.0f;
            bool pred = false;
            if (j < NPTS) {
                d = dist3(sx[j], sy[j], sz[j], qx, qy, qz);
                pred = (d <= R1SQ);
            }
            unsigned long long mb = __ballot(pred);
            if (pred) {
                int pos = cn + __popcll(mb & ((1ull << lane) - 1ull));
                if (pos < CANDCAP) { candd[wid][pos] = d; candi[wid][pos] = j; }
            }
            cn += __popcll(mb);
        }
        if (cn > CANDCAP) cn = CANDCAP;

        float fmx[5];
#pragma unroll
        for (int f = 0; f < 5; f++) fmx[f] = -1e30f;
        for (int t = lane; t < cn; t += 64) {
            float d = candd[wid][t];
            int j = candi[wid][t];
            bool valid = true;
            if (cn > KNN) {
                int rank = 0;
                for (int u = 0; u < cn; u++) {
                    float du = candd[wid][u];
                    int iu = candi[wid][u];
                    rank += (du < d || (du == d && iu < j)) ? 1 : 0;
                }
                valid = (rank < KNN);   // replicates top_k stability (ties -> lower idx)
            }
            if (valid) {
                float rx = (sx[j] - qx) / 0.3f;
                float ry = (sy[j] - qy) / 0.3f;
                float rz = (sz[j] - qz) / 0.3f;
#pragma unroll
                for (int f = 0; f < 5; f++) {
                    float h = fmaf(rx, w1s[f], fmaf(ry, w1s[5 + f], fmaf(rz, w1s[10 + f], b1s[f])));
                    h = fmaxf(h, 0.0f);
                    fmx[f] = fmaxf(fmx[f], h);
                }
            }
        }
#pragma unroll
        for (int off = 32; off > 0; off >>= 1) {
#pragma unroll
            for (int f = 0; f < 5; f++) fmx[f] = fmaxf(fmx[f], __shfl_xor(fmx[f], off));
        }
        if (lane == 0) {
#pragma unroll
            for (int f = 0; f < 5; f++) f1s[s][f] = fmx[f];
        }
    }
    __syncthreads();

    // ---- wave 0: FPS2, knn2 + MLP2 -> f2, MLP3 -> latent ----
    if (wid == 0) {
        // FPS2: 5 from 100
        float m2a = 1e10f, m2b = 1e10f;
        int last2 = 0;
        for (int it = 0; it < M2C; ++it) {
            if (lane == 0) fps2[it] = last2;
            float qx = smpx[last2], qy = smpy[last2], qz = smpz[last2];
            float bv = -1.0f;
            int bi = 0x7fffffff;
            {
                int j = lane;
                float d = dist3(smpx[j], smpy[j], smpz[j], qx, qy, qz);
                m2a = fminf(m2a, d);
                if (m2a > bv) { bv = m2a; bi = j; }
            }
            {
                int j = lane + 64;
                if (j < M1C) {
                    float d = dist3(smpx[j], smpy[j], smpz[j], qx, qy, qz);
                    m2b = fminf(m2b, d);
                    if (m2b > bv) { bv = m2b; bi = j; }
                }
            }
            waveArgmax(bv, bi);
            last2 = bi;
        }
        if (lane < M2C) {
            int j = fps2[lane];
            s2x[lane] = smpx[j]; s2y[lane] = smpy[j]; s2z[lane] = smpz[j];
        }

        // knn2 + MLP2 -> f2
        for (int s = 0; s < M2C; ++s) {
            float qx = s2x[s], qy = s2y[s], qz = s2z[s];
            int cn = 0;
            for (int c = 0; c < 2; c++) {
                int j = c * 64 + lane;
                float d = 0.0f;
                bool pred = false;
                if (j < M1C) {
                    d = dist3(smpx[j], smpy[j], smpz[j], qx, qy, qz);
                    pred = (d <= R2SQ);
                }
                unsigned long long mb = __ballot(pred);
                if (pred) {
                    int pos = cn + __popcll(mb & ((1ull << lane) - 1ull));
                    candd[0][pos] = d; candi[0][pos] = j;   // cn<=100 < CANDCAP
                }
                cn += __popcll(mb);
            }
            float hmx[25];
#pragma unroll
            for (int f = 0; f < 25; f++) hmx[f] = -1e30f;
            for (int t = lane; t < cn; t += 64) {
                float d = candd[0][t];
                int j = candi[0][t];
                bool valid = true;
                if (cn > KNN) {
                    int rank = 0;
                    for (int u = 0; u < cn; u++) {
                        float du = candd[0][u];
                        int iu = candi[0][u];
                        rank += (du < d || (du == d && iu < j)) ? 1 : 0;
                    }
                    valid = (rank < KNN);
                }
                if (valid) {
                    float in8[8];
                    in8[0] = (smpx[j] - qx) / 1.0f;
                    in8[1] = (smpy[j] - qy) / 1.0f;
                    in8[2] = (smpz[j] - qz) / 1.0f;
                    in8[3] = f1s[j][0]; in8[4] = f1s[j][1]; in8[5] = f1s[j][2];
                    in8[6] = f1s[j][3]; in8[7] = f1s[j][4];
#pragma unroll
                    for (int f = 0; f < 25; f++) {
                        float h = b2s[f];
#pragma unroll
                        for (int i = 0; i < 8; i++) h = fmaf(in8[i], w2s[i * 25 + f], h);
                        h = fmaxf(h, 0.0f);
                        hmx[f] = fmaxf(hmx[f], h);
                    }
                }
            }
#pragma unroll
            for (int off = 32; off > 0; off >>= 1) {
#pragma unroll
                for (int f = 0; f < 25; f++) hmx[f] = fmaxf(hmx[f], __shfl_xor(hmx[f], off));
            }
            if (lane == 0) {
#pragma unroll
                for (int f = 0; f < 25; f++) f2s[s][f] = hmx[f];
            }
        }

        // MLP3 + max-pool -> latent (45)
        if (lane < 45) {
            float lm = -1e30f;
            for (int r = 0; r < M2C; r++) {
                float h = b3s[lane];
                h = fmaf(s2x[r] / 2.0f, w3s[0 * 45 + lane], h);
                h = fmaf(s2y[r] / 2.0f, w3s[1 * 45 + lane], h);
                h = fmaf(s2z[r] / 2.0f, w3s[2 * 45 + lane], h);
#pragma unroll
                for (int i = 0; i < 25; i++) h = fmaf(f2s[r][i], w3s[(3 + i) * 45 + lane], h);
                h = fmaxf(h, 0.0f);
                lm = fmaxf(lm, h);
            }
            latent[lane] = lm;
        }
    }
    __syncthreads();

    // ---- decoder stage 1: o1 = latent @ D1 + bD1 -> (5, 28) ----
    for (int t = tid; t < 140; t += TPB) {
        float acc = bD1[t];
        for (int i = 0; i < 45; i++) acc = fmaf(latent[i], D1[i * 140 + t], acc);
        int r = t / 28, c = t % 28;
        if (c < 3) decv[r][c] = acc;
        else cfs[r][c - 3] = fmaxf(acc, 0.0f);
    }
    __syncthreads();

    // ---- decoder stage 2: o2 = cf @ D2 + bD2 -> (100, 8) ----
    for (int t = tid; t < 800; t += TPB) {
        int r = t / 160, c = t % 160;
        float acc = bD2[c];
        for (int i = 0; i < 25; i++) acc = fmaf(cfs[r][i], D2[i * 160 + c], acc);
        int g = r * 20 + c / 8, c8 = c % 8;
        if (c8 < 3) dec2s[g][c8] = acc;
        else cf2s[g][c8 - 3] = fmaxf(acc, 0.0f);
    }
    __syncthreads();

    // ---- decoder stage 3 + compose output ----
    float* outb = out + (size_t)b * (NPTS * 3);
    for (int t = tid; t < NPTS * 3; t += TPB) {
        int n = t / 3, c = t % 3;
        int g = n / 20;          // dec2 row
        int m = n / 400;         // dec row
        int r60 = (n % 20) * 3 + c;
        float acc = bD3[r60];
        for (int i = 0; i < 5; i++) acc = fmaf(cf2s[g][i], D3[i * 60 + r60], acc);
        // out = ((dec*R3 + dec2)*R2 + dec3)*R1, R2 = 1
        float val = ((decv[m][c] * 2.0f + dec2s[g][c]) + acc) * 0.3f;
        outb[t] = val;
    }
}

extern "C" void kernel_launch(void* const* d_in, const int* in_sizes, int n_in,
                              void* d_out, int out_size, void* d_ws, size_t ws_size,
                              hipStream_t stream) {
    const float* P   = (const float*)d_in[0];
    const float* W1  = (const float*)d_in[1];
    const float* b1  = (const float*)d_in[2];
    const float* W2  = (const float*)d_in[3];
    const float* b2  = (const float*)d_in[4];
    const float* W3  = (const float*)d_in[5];
    const float* b3  = (const float*)d_in[6];
    const float* D1  = (const float*)d_in[7];
    const float* bD1 = (const float*)d_in[8];
    const float* D2  = (const float*)d_in[9];
    const float* bD2 = (const float*)d_in[10];
    const float* D3  = (const float*)d_in[11];
    const float* bD3 = (const float*)d_in[12];
    float* out = (float*)d_out;

    int B = in_sizes[0] / (NPTS * 3);
    hipLaunchKernelGGL(pointnet_kernel, dim3(B), dim3(TPB), 0, stream,
                       P, W1, b1, W2, b2, W3, b3, D1, bD1, D2, bD2, D3, bD3, out);
}

// Round 2
// 241.669 us; speedup vs baseline: 1.1976x; 1.1976x over previous
//
#include <hip/hip_runtime.h>

#define TPB 256
#define NPTS 2000
#define M1C 100
#define M2C 5
#define KNN 20
#define CANDCAP 128

// Bitwise-exact squared distance matching numpy/jax fp32 sequential sum:
// ((dx*dx + dy*dy) + dz*dz), no FMA contraction.
__device__ __forceinline__ float dist3(float px, float py, float pz,
                                       float qx, float qy, float qz) {
#pragma clang fp contract(off)
    float dx = px - qx, dy = py - qy, dz = pz - qz;
    return dx * dx + dy * dy + dz * dz;
}
__device__ __forceinline__ float dist3d(float px, float py, float pz,
                                        float qx, float qy, float qz,
                                        float& dx, float& dy, float& dz) {
#pragma clang fp contract(off)
    dx = px - qx; dy = py - qy; dz = pz - qz;
    return dx * dx + dy * dy + dz * dz;
}

// Wave64 max-reduce via DPP (VALU pipe, no LDS). LLVM AtomicOptimizer pattern:
// row_shr 1,2,4,8 (row_mask 0xf) then row_bcast15 (0xa), row_bcast31 (0xc);
// full-wave result lands in lane 63, broadcast via readlane.
#define DPP_STEP_F(x, ctrl, rm)                                                      \
    do {                                                                             \
        float _t = __int_as_float(__builtin_amdgcn_update_dpp(                       \
            (int)0xff800000, __float_as_int(x), ctrl, rm, 0xf, false));              \
        x = fmaxf(x, _t);                                                            \
    } while (0)

__device__ __forceinline__ float wave_fmax(float x) {
    DPP_STEP_F(x, 0x111, 0xf);
    DPP_STEP_F(x, 0x112, 0xf);
    DPP_STEP_F(x, 0x114, 0xf);
    DPP_STEP_F(x, 0x118, 0xf);
    DPP_STEP_F(x, 0x142, 0xa);
    DPP_STEP_F(x, 0x143, 0xc);
    return __int_as_float(__builtin_amdgcn_readlane(__float_as_int(x), 63));
}

#define DPP_STEP_I(x, ctrl, rm)                                                      \
    do {                                                                             \
        int _t = __builtin_amdgcn_update_dpp(0x7fffffff, x, ctrl, rm, 0xf, false);   \
        x = min(x, _t);                                                              \
    } while (0)

__device__ __forceinline__ int wave_imin(int x) {
    DPP_STEP_I(x, 0x111, 0xf);
    DPP_STEP_I(x, 0x112, 0xf);
    DPP_STEP_I(x, 0x114, 0xf);
    DPP_STEP_I(x, 0x118, 0xf);
    DPP_STEP_I(x, 0x142, 0xa);
    DPP_STEP_I(x, 0x143, 0xc);
    return __builtin_amdgcn_readlane(x, 63);
}

__global__ __launch_bounds__(TPB) void pointnet_kernel(
    const float* __restrict__ P,
    const float* __restrict__ W1, const float* __restrict__ b1,
    const float* __restrict__ W2, const float* __restrict__ b2,
    const float* __restrict__ W3, const float* __restrict__ b3,
    const float* __restrict__ D1, const float* __restrict__ bD1,
    const float* __restrict__ D2, const float* __restrict__ bD2,
    const float* __restrict__ D3, const float* __restrict__ bD3,
    float* __restrict__ out)
{
    __shared__ float sP[3][NPTS];
    __shared__ float smpx[M1C], smpy[M1C], smpz[M1C];
    __shared__ float s2x[M2C], s2y[M2C], s2z[M2C];
    __shared__ unsigned f1u[M1C][5];       // relu>=0: uint bits compare as float
    __shared__ int   cnw[4][M1C];          // per-wave within-radius counts
    __shared__ float f2s[M2C][25];
    __shared__ float latent[45];
    __shared__ float decv[M2C][3];
    __shared__ float cfs[M2C][25];
    __shared__ float dec2s[M1C][3];
    __shared__ float cf2s[M1C][5];
    __shared__ float candd[4][CANDCAP];
    __shared__ int   candi[4][CANDCAP];
    __shared__ float rvv[2][4];            // parity double-buffered argmax slots
    __shared__ int   rvi[2][4];
    __shared__ float w2s[200], b2s[25], w3s[1260], b3s[45];

    const int b = blockIdx.x;
    const int tid = threadIdx.x;
    const int lane = tid & 63;
    const int wid = tid >> 6;
    float* sx = sP[0]; float* sy = sP[1]; float* sz = sP[2];

    // must match f32(python_float r*r): computed in f64 then cast
    const float R1SQ = (float)(0.3 * 0.3);
    const float R2SQ = 1.0f;
    const float INVR1 = 1.0f / 0.3f;

    // ---- stage points (SoA, vectorized) + small weights ----
    const float* Pb = P + (size_t)b * (NPTS * 3);
    const float4* P4 = (const float4*)Pb;
    for (int i = tid; i < (NPTS * 3) / 4; i += TPB) {
        float4 f = P4[i];
        int j = 4 * i;
        float v[4] = {f.x, f.y, f.z, f.w};
#pragma unroll
        for (int e = 0; e < 4; ++e) {
            int jj = j + e;
            (&sP[0][0])[(jj % 3) * NPTS + jj / 3] = v[e];
        }
    }
    for (int t = tid; t < M1C * 5; t += TPB) ((unsigned*)f1u)[t] = 0u;
    for (int t = tid; t < 200; t += TPB) w2s[t] = W2[t];
    for (int t = tid; t < 25; t += TPB) b2s[t] = b2[t];
    for (int t = tid; t < 1260; t += TPB) w3s[t] = W3[t];
    for (int t = tid; t < 45; t += TPB) b3s[t] = b3[t];
    float rw1[15], rb1[5];
#pragma unroll
    for (int i = 0; i < 15; ++i) rw1[i] = W1[i];
#pragma unroll
    for (int i = 0; i < 5; ++i) rb1[i] = b1[i];
    __syncthreads();

    // ---- points into registers (8 per lane) ----
    float px[8], py[8], pz[8], mind[8];
#pragma unroll
    for (int k = 0; k < 8; ++k) {
        int j = tid + (k << 8);
        bool v = j < NPTS;
        int jc = v ? j : 0;
        px[k] = v ? sx[jc] : 1e18f;
        py[k] = v ? sy[jc] : 1e18f;
        pz[k] = v ? sz[jc] : 1e18f;
        mind[k] = v ? 1e10f : -1.0f;
    }

    // ---- FPS1 fused with knn1 pass A ----
    // iteration it's query IS sample it; reuse dx,dy,dz for radius test + MLP1.
    int last = 0;
    for (int it = 0; it < M1C; ++it) {
        float qx = sx[last], qy = sy[last], qz = sz[last];
        if (tid == 0) { smpx[it] = qx; smpy[it] = qy; smpz[it] = qz; }
        float bv = -1.0f; int bi = 0x7fffffff;
        int cntw = 0;
#pragma unroll
        for (int k = 0; k < 8; ++k) {
            float dx, dy, dz;
            float d = dist3d(px[k], py[k], pz[k], qx, qy, qz, dx, dy, dz);
            float m = fminf(mind[k], d);
            mind[k] = m;
            if (m > bv) { bv = m; bi = tid + (k << 8); }   // strict >: min-idx ties
            bool hit = (d <= R1SQ);
            cntw += (int)__popcll(__ballot(hit));
            if (hit) {
                float rx = dx * INVR1, ry = dy * INVR1, rz = dz * INVR1;
#pragma unroll
                for (int f = 0; f < 5; ++f) {
                    float h = fmaf(rx, rw1[f], fmaf(ry, rw1[5 + f], fmaf(rz, rw1[10 + f], rb1[f])));
                    h = fmaxf(h, 0.0f);
                    atomicMax(&f1u[it][f], __float_as_uint(h));
                }
            }
        }
        float wv = wave_fmax(bv);
        int cand = (bv == wv) ? bi : 0x7fffffff;
        int wi = wave_imin(cand);
        int p = it & 1;
        if (lane == 0) { rvv[p][wid] = wv; rvi[p][wid] = wi; cnw[wid][it] = cntw; }
        __syncthreads();
        float v0 = rvv[p][0]; int i0 = rvi[p][0];
#pragma unroll
        for (int w = 1; w < 4; ++w) {
            float vw = rvv[p][w]; int iw = rvi[p][w];
            if (vw > v0 || (vw == v0 && iw < i0)) { v0 = vw; i0 = iw; }
        }
        last = i0;
    }
    __syncthreads();

    // ---- phase: wave0 does FPS2; waves 1-3 fix up samples with cn>20 ----
    if (wid == 0) {
        float ax = smpx[lane], ay = smpy[lane], az = smpz[lane];
        bool vb = lane < (M1C - 64);
        float bx2 = vb ? smpx[lane + 64] : 1e18f;
        float by2 = vb ? smpy[lane + 64] : 1e18f;
        float bz2 = vb ? smpz[lane + 64] : 1e18f;
        float m2a = 1e10f;
        float m2b = vb ? 1e10f : -1.0f;
        int last2 = 0;
        for (int it = 0; it < M2C; ++it) {
            float qx = smpx[last2], qy = smpy[last2], qz = smpz[last2];
            if (lane == 0) { s2x[it] = qx; s2y[it] = qy; s2z[it] = qz; }
            float da = dist3(ax, ay, az, qx, qy, qz);
            m2a = fminf(m2a, da);
            float db = dist3(bx2, by2, bz2, qx, qy, qz);
            m2b = fminf(m2b, db);
            float bv = m2a; int bi = lane;
            if (m2b > bv) { bv = m2b; bi = lane + 64; }
            float wv = wave_fmax(bv);
            int cand = (bv == wv) ? bi : 0x7fffffff;
            last2 = wave_imin(cand);
        }
    } else {
        int c0 = cnw[0][lane] + cnw[1][lane] + cnw[2][lane] + cnw[3][lane];
        unsigned long long bm0 = __ballot(c0 > KNN);
        int l1 = lane + 64;
        int c1 = 0;
        if (l1 < M1C) c1 = cnw[0][l1] + cnw[1][l1] + cnw[2][l1] + cnw[3][l1];
        unsigned long long bm1 = __ballot(c1 > KNN);
        int ord = 0;
        for (int half = 0; half < 2; ++half) {
            unsigned long long m = half ? bm1 : bm0;
            while (m) {
                int bpos = __builtin_ctzll(m);
                m &= m - 1;
                int s = bpos + (half ? 64 : 0);
                if (ord % 3 == wid - 1) {
                    // rank-filtered recompute of f1[s] (overwrites pass-A value)
                    float qx = smpx[s], qy = smpy[s], qz = smpz[s];
                    int cn = 0;
                    for (int c = 0; c < 32; ++c) {
                        int j = c * 64 + lane;
                        float d = 0.0f; bool pred = false;
                        if (j < NPTS) {
                            d = dist3(sx[j], sy[j], sz[j], qx, qy, qz);
                            pred = (d <= R1SQ);
                        }
                        unsigned long long mb = __ballot(pred);
                        if (pred) {
                            int pos = cn + (int)__popcll(mb & ((1ull << lane) - 1ull));
                            if (pos < CANDCAP) { candd[wid][pos] = d; candi[wid][pos] = j; }
                        }
                        cn += (int)__popcll(mb);
                    }
                    if (cn > CANDCAP) cn = CANDCAP;
                    float fmx[5];
#pragma unroll
                    for (int f = 0; f < 5; ++f) fmx[f] = -1e30f;
                    for (int t = lane; t < cn; t += 64) {
                        float d = candd[wid][t]; int j = candi[wid][t];
                        int rank = 0;
                        for (int u = 0; u < cn; ++u) {
                            float du = candd[wid][u]; int iu = candi[wid][u];
                            rank += (du < d || (du == d && iu < j)) ? 1 : 0;
                        }
                        if (rank < KNN) {   // replicates top_k stability (ties -> lower idx)
                            float rx = (sx[j] - qx) * INVR1;
                            float ry = (sy[j] - qy) * INVR1;
                            float rz = (sz[j] - qz) * INVR1;
#pragma unroll
                            for (int f = 0; f < 5; ++f) {
                                float h = fmaf(rx, rw1[f], fmaf(ry, rw1[5 + f], fmaf(rz, rw1[10 + f], rb1[f])));
                                fmx[f] = fmaxf(fmx[f], fmaxf(h, 0.0f));
                            }
                        }
                    }
#pragma unroll
                    for (int f = 0; f < 5; ++f) {
                        float mx = wave_fmax(fmx[f]);
                        if (lane == 0) f1u[s][f] = __float_as_uint(mx);
                    }
                }
                ord++;
            }
        }
    }
    __syncthreads();

    // ---- knn2 + MLP2 -> f2 (samples parallel across waves) ----
    for (int s = wid; s < M2C; s += 4) {
        float qx = s2x[s], qy = s2y[s], qz = s2z[s];
        int cn = 0;
#pragma unroll
        for (int c = 0; c < 2; ++c) {
            int j = c * 64 + lane;
            float d = 0.0f; bool pred = false;
            if (j < M1C) {
                d = dist3(smpx[j], smpy[j], smpz[j], qx, qy, qz);
                pred = (d <= R2SQ);
            }
            unsigned long long mb = __ballot(pred);
            if (pred) {
                int pos = cn + (int)__popcll(mb & ((1ull << lane) - 1ull));
                candd[wid][pos] = d; candi[wid][pos] = j;   // cn<=100<CANDCAP
            }
            cn += (int)__popcll(mb);
        }
        float hmx[25];
#pragma unroll
        for (int f = 0; f < 25; ++f) hmx[f] = -1e30f;
        for (int t = lane; t < cn; t += 64) {
            float d = candd[wid][t]; int j = candi[wid][t];
            bool valid = true;
            if (cn > KNN) {
                int rank = 0;
                for (int u = 0; u < cn; ++u) {
                    float du = candd[wid][u]; int iu = candi[wid][u];
                    rank += (du < d || (du == d && iu < j)) ? 1 : 0;
                }
                valid = rank < KNN;
            }
            if (valid) {
                float in8[8];
                in8[0] = smpx[j] - qx; in8[1] = smpy[j] - qy; in8[2] = smpz[j] - qz;
#pragma unroll
                for (int f = 0; f < 5; ++f) in8[3 + f] = __uint_as_float(f1u[j][f]);
#pragma unroll
                for (int f = 0; f < 25; ++f) {
                    float h = b2s[f];
#pragma unroll
                    for (int i = 0; i < 8; ++i) h = fmaf(in8[i], w2s[i * 25 + f], h);
                    hmx[f] = fmaxf(hmx[f], fmaxf(h, 0.0f));
                }
            }
        }
#pragma unroll
        for (int f = 0; f < 25; ++f) {
            float mx = wave_fmax(hmx[f]);
            if (lane == 0) f2s[s][f] = mx;
        }
    }
    __syncthreads();

    // ---- MLP3 + max-pool -> latent (45) ----
    if (wid == 0 && lane < 45) {
        float lm = -1e30f;
        for (int r = 0; r < M2C; ++r) {
            float h = b3s[lane];
            h = fmaf(s2x[r] * 0.5f, w3s[0 * 45 + lane], h);
            h = fmaf(s2y[r] * 0.5f, w3s[1 * 45 + lane], h);
            h = fmaf(s2z[r] * 0.5f, w3s[2 * 45 + lane], h);
#pragma unroll
            for (int i = 0; i < 25; ++i) h = fmaf(f2s[r][i], w3s[(3 + i) * 45 + lane], h);
            lm = fmaxf(lm, fmaxf(h, 0.0f));
        }
        latent[lane] = lm;
    }
    __syncthreads();

    // ---- decoder stage 1: latent @ D1 + bD1 -> (5, 28) ----
    for (int t = tid; t < 140; t += TPB) {
        float acc = bD1[t];
        for (int i = 0; i < 45; i++) acc = fmaf(latent[i], D1[i * 140 + t], acc);
        int r = t / 28, c = t % 28;
        if (c < 3) decv[r][c] = acc;
        else cfs[r][c - 3] = fmaxf(acc, 0.0f);
    }
    __syncthreads();

    // ---- decoder stage 2: cf @ D2 + bD2 -> (100, 8) ----
    for (int t = tid; t < 800; t += TPB) {
        int r = t / 160, c = t % 160;
        float acc = bD2[c];
        for (int i = 0; i < 25; i++) acc = fmaf(cfs[r][i], D2[i * 160 + c], acc);
        int g = r * 20 + c / 8, c8 = c % 8;
        if (c8 < 3) dec2s[g][c8] = acc;
        else cf2s[g][c8 - 3] = fmaxf(acc, 0.0f);
    }
    __syncthreads();

    // ---- decoder stage 3 + compose output ----
    float* outb = out + (size_t)b * (NPTS * 3);
    for (int t = tid; t < NPTS * 3; t += TPB) {
        int n = t / 3, c = t % 3;
        int g = n / 20;
        int m = n / 400;
        int r60 = (n % 20) * 3 + c;
        float acc = bD3[r60];
        for (int i = 0; i < 5; i++) acc = fmaf(cf2s[g][i], D3[i * 60 + r60], acc);
        // out = ((dec*R3 + dec2)*R2 + dec3)*R1, R2 = 1
        float val = ((decv[m][c] * 2.0f + dec2s[g][c]) + acc) * 0.3f;
        outb[t] = val;
    }
}

extern "C" void kernel_launch(void* const* d_in, const int* in_sizes, int n_in,
                              void* d_out, int out_size, void* d_ws, size_t ws_size,
                              hipStream_t stream) {
    const float* P   = (const float*)d_in[0];
    const float* W1  = (const float*)d_in[1];
    const float* b1  = (const float*)d_in[2];
    const float* W2  = (const float*)d_in[3];
    const float* b2  = (const float*)d_in[4];
    const float* W3  = (const float*)d_in[5];
    const float* b3  = (const float*)d_in[6];
    const float* D1  = (const float*)d_in[7];
    const float* bD1 = (const float*)d_in[8];
    const float* D2  = (const float*)d_in[9];
    const float* bD2 = (const float*)d_in[10];
    const float* D3  = (const float*)d_in[11];
    const float* bD3 = (const float*)d_in[12];
    float* out = (float*)d_out;

    int B = in_sizes[0] / (NPTS * 3);
    hipLaunchKernelGGL(pointnet_kernel, dim3(B), dim3(TPB), 0, stream,
                       P, W1, b1, W2, b2, W3, b3, D1, bD1, D2, bD2, D3, bD3, out);
}

// Round 3
// 219.811 us; speedup vs baseline: 1.3167x; 1.0994x over previous
//
#include <hip/hip_runtime.h>

#define TPB 512
#define NW 8
#define NPTS 2000
#define M1C 100
#define M2C 5
#define KNN 20
#define CAP 64
#define CANDCAP 128

// Bitwise-exact squared distance matching numpy/jax fp32 sequential sum:
// ((dx*dx + dy*dy) + dz*dz), no FMA contraction.
__device__ __forceinline__ float dist3(float px, float py, float pz,
                                       float qx, float qy, float qz) {
#pragma clang fp contract(off)
    float dx = px - qx, dy = py - qy, dz = pz - qz;
    return dx * dx + dy * dy + dz * dz;
}
__device__ __forceinline__ float dist3d(float px, float py, float pz,
                                        float qx, float qy, float qz,
                                        float& dx, float& dy, float& dz) {
#pragma clang fp contract(off)
    dx = px - qx; dy = py - qy; dz = pz - qz;
    return dx * dx + dy * dy + dz * dz;
}

// Fused wave64 (value,index) argmax, min-index tie-break, via one DPP chain.
// LLVM AtomicOptimizer pattern: row_shr 1,2,4,8 then row_bcast15/31; result
// lands in lane 63, broadcast by readlane. Inactive source -> (-inf, INT_MAX)
// which never wins (strict > on value; v >= -1 > -inf always).
#define ARGMAX_STEP(ctrl, rm)                                                        \
    do {                                                                             \
        float ov = __int_as_float(__builtin_amdgcn_update_dpp(                       \
            (int)0xff800000, __float_as_int(v), ctrl, rm, 0xf, false));              \
        int oi = __builtin_amdgcn_update_dpp(0x7fffffff, i, ctrl, rm, 0xf, false);   \
        bool take = (ov > v) || (ov == v && oi < i);                                 \
        v = take ? ov : v;                                                           \
        i = take ? oi : i;                                                           \
    } while (0)

__device__ __forceinline__ void wave_argmax(float& v, int& i) {
    ARGMAX_STEP(0x111, 0xf);
    ARGMAX_STEP(0x112, 0xf);
    ARGMAX_STEP(0x114, 0xf);
    ARGMAX_STEP(0x118, 0xf);
    ARGMAX_STEP(0x142, 0xa);
    ARGMAX_STEP(0x143, 0xc);
    v = __int_as_float(__builtin_amdgcn_readlane(__float_as_int(v), 63));
    i = __builtin_amdgcn_readlane(i, 63);
}

// Value-only wave max (for feature reductions).
#define FMAX_STEP(ctrl, rm)                                                          \
    do {                                                                             \
        float _t = __int_as_float(__builtin_amdgcn_update_dpp(                       \
            (int)0xff800000, __float_as_int(x), ctrl, rm, 0xf, false));              \
        x = fmaxf(x, _t);                                                            \
    } while (0)

__device__ __forceinline__ float wave_fmax(float x) {
    FMAX_STEP(0x111, 0xf);
    FMAX_STEP(0x112, 0xf);
    FMAX_STEP(0x114, 0xf);
    FMAX_STEP(0x118, 0xf);
    FMAX_STEP(0x142, 0xa);
    FMAX_STEP(0x143, 0xc);
    return __int_as_float(__builtin_amdgcn_readlane(__float_as_int(x), 63));
}

__global__ __launch_bounds__(TPB) void pointnet_kernel(
    const float* __restrict__ P,
    const float* __restrict__ W1, const float* __restrict__ b1,
    const float* __restrict__ W2, const float* __restrict__ b2,
    const float* __restrict__ W3, const float* __restrict__ b3,
    const float* __restrict__ D1, const float* __restrict__ bD1,
    const float* __restrict__ D2, const float* __restrict__ bD2,
    const float* __restrict__ D3, const float* __restrict__ bD3,
    float* __restrict__ out)
{
    __shared__ float sP[3][NPTS];
    __shared__ float smpx[M1C], smpy[M1C], smpz[M1C];
    __shared__ float s2x[M2C], s2y[M2C], s2z[M2C];
    __shared__ int   cnt[M1C];
    __shared__ float candd[M1C * CAP];
    __shared__ int   candi[M1C * CAP];
    __shared__ float f1s[M1C][5];
    __shared__ float f2s[M2C][25];
    __shared__ float latent[45];
    __shared__ float decv[M2C][3];
    __shared__ float cfs[M2C][25];
    __shared__ float dec2s[M1C][3];
    __shared__ float cf2s[M1C][5];
    __shared__ float kn2d[NW][CANDCAP];
    __shared__ int   kn2i[NW][CANDCAP];
    __shared__ __align__(16) float rvv[2][NW];   // parity double-buffered
    __shared__ __align__(16) int   rvi[2][NW];
    __shared__ float w2s[200], b2s[25], w3s[1260], b3s[45];

    const int b = blockIdx.x;
    const int tid = threadIdx.x;
    const int lane = tid & 63;
    const int wid = tid >> 6;
    float* sx = sP[0]; float* sy = sP[1]; float* sz = sP[2];

    // must match f32(python_float r*r): computed in f64 then cast
    const float R1SQ = (float)(0.3 * 0.3);
    const float R2SQ = 1.0f;
    const float INVR1 = 1.0f / 0.3f;

    // ---- stage points (SoA, vectorized) + weights ----
    const float* Pb = P + (size_t)b * (NPTS * 3);
    const float4* P4 = (const float4*)Pb;
    for (int i = tid; i < (NPTS * 3) / 4; i += TPB) {
        float4 f = P4[i];
        int j = 4 * i;
        float v[4] = {f.x, f.y, f.z, f.w};
#pragma unroll
        for (int e = 0; e < 4; ++e) {
            int jj = j + e;
            (&sP[0][0])[(jj % 3) * NPTS + jj / 3] = v[e];
        }
    }
    for (int t = tid; t < M1C; t += TPB) cnt[t] = 0;
    for (int t = tid; t < 200; t += TPB) w2s[t] = W2[t];
    for (int t = tid; t < 25; t += TPB) b2s[t] = b2[t];
    for (int t = tid; t < 1260; t += TPB) w3s[t] = W3[t];
    for (int t = tid; t < 45; t += TPB) b3s[t] = b3[t];
    float rw1[15], rb1[5];
#pragma unroll
    for (int i = 0; i < 15; ++i) rw1[i] = W1[i];
#pragma unroll
    for (int i = 0; i < 5; ++i) rb1[i] = b1[i];
    __syncthreads();

    // ---- points into registers (4 per lane at TPB=512) ----
    float px[4], py[4], pz[4], mind[4];
#pragma unroll
    for (int k = 0; k < 4; ++k) {
        int j = tid + (k << 9);
        bool v = j < NPTS;
        int jc = v ? j : 0;
        px[k] = v ? sx[jc] : 1e18f;
        py[k] = v ? sy[jc] : 1e18f;
        pz[k] = v ? sz[jc] : 1e18f;
        mind[k] = v ? 1e10f : -1.0f;
    }

    // ---- FPS1 with inline hit recording (MLP deferred) ----
    float qx = sx[0], qy = sy[0], qz = sz[0];
    for (int it = 0; it < M1C; ++it) {
        if (tid == 0) { smpx[it] = qx; smpy[it] = qy; smpz[it] = qz; }
        float bv = -1.0f; int bi = 0x7fffffff;
#pragma unroll
        for (int k = 0; k < 4; ++k) {
            int j = tid + (k << 9);
            float dx, dy, dz;
            float d = dist3d(px[k], py[k], pz[k], qx, qy, qz, dx, dy, dz);
            float m = fminf(mind[k], d);
            mind[k] = m;
            if (m > bv) { bv = m; bi = j; }     // strict >: min-idx ties
            if (d <= R1SQ) {
                int pos = atomicAdd(&cnt[it], 1);
                if (pos < CAP) { candd[it * CAP + pos] = d; candi[it * CAP + pos] = j; }
            }
        }
        if (it == M1C - 1) break;               // last sample needs no successor
        wave_argmax(bv, bi);
        int p = it & 1;
        if (lane == 0) { rvv[p][wid] = bv; rvi[p][wid] = bi; }
        __syncthreads();
        float4 va = *(const float4*)&rvv[p][0];
        float4 vb = *(const float4*)&rvv[p][4];
        int4 ia = *(const int4*)&rvi[p][0];
        int4 ib = *(const int4*)&rvi[p][4];
        float cv = va.x; int ci = ia.x;
#define SEL(vv, ii) { bool t = ((vv) > cv) || ((vv) == cv && (ii) < ci); cv = t ? (vv) : cv; ci = t ? (ii) : ci; }
        SEL(va.y, ia.y) SEL(va.z, ia.z) SEL(va.w, ia.w)
        SEL(vb.x, ib.x) SEL(vb.y, ib.y) SEL(vb.z, ib.z) SEL(vb.w, ib.w)
#undef SEL
        qx = sx[ci]; qy = sy[ci]; qz = sz[ci];
    }
    __syncthreads();

    // ---- post-phase: wave0 FPS2; waves 1-7 MLP1 from stored candidates ----
    if (wid == 0) {
        float ax = smpx[lane], ay = smpy[lane], az = smpz[lane];
        bool vb2 = lane < (M1C - 64);
        float bx2 = vb2 ? smpx[lane + 64] : 1e18f;
        float by2 = vb2 ? smpy[lane + 64] : 1e18f;
        float bz2 = vb2 ? smpz[lane + 64] : 1e18f;
        float m2a = 1e10f;
        float m2b = vb2 ? 1e10f : -1.0f;
        int last2 = 0;
        for (int it = 0; it < M2C; ++it) {
            float fx = smpx[last2], fy = smpy[last2], fz = smpz[last2];
            if (lane == 0) { s2x[it] = fx; s2y[it] = fy; s2z[it] = fz; }
            m2a = fminf(m2a, dist3(ax, ay, az, fx, fy, fz));
            m2b = fminf(m2b, dist3(bx2, by2, bz2, fx, fy, fz));
            float v = m2a; int i = lane;
            if (m2b > v) { v = m2b; i = lane + 64; }
            wave_argmax(v, i);
            last2 = i;
        }
    } else {
        for (int s = wid - 1; s < M1C; s += (NW - 1)) {
            int cn = cnt[s];
            float qx2 = smpx[s], qy2 = smpy[s], qz2 = smpz[s];
            float fmx[5];
#pragma unroll
            for (int f = 0; f < 5; ++f) fmx[f] = -1e30f;
            if (cn <= CAP) {
                // single pass: lane t owns candidate t (cn <= 64)
                if (lane < cn) {
                    float d = candd[s * CAP + lane];
                    int j = candi[s * CAP + lane];
                    bool valid = true;
                    if (cn > KNN) {
                        int rank = 0;
                        for (int u = 0; u < cn; ++u) {
                            float du = candd[s * CAP + u];
                            int iu = candi[s * CAP + u];
                            rank += (du < d || (du == d && iu < j)) ? 1 : 0;
                        }
                        valid = rank < KNN;   // replicates top_k stability (ties -> lower idx)
                    }
                    if (valid) {
                        float rx = (sx[j] - qx2) * INVR1;
                        float ry = (sy[j] - qy2) * INVR1;
                        float rz = (sz[j] - qz2) * INVR1;
#pragma unroll
                        for (int f = 0; f < 5; ++f) {
                            float h = fmaf(rx, rw1[f], fmaf(ry, rw1[5 + f], fmaf(rz, rw1[10 + f], rb1[f])));
                            fmx[f] = fmaxf(fmx[f], fmaxf(h, 0.0f));
                        }
                    }
                }
            } else {
                // overflow fallback (statistically never): full rescan
                int cn2 = 0;
                for (int c = 0; c < 32; ++c) {
                    int j = c * 64 + lane;
                    float d = 0.0f; bool pred = false;
                    if (j < NPTS) {
                        d = dist3(sx[j], sy[j], sz[j], qx2, qy2, qz2);
                        pred = (d <= R1SQ);
                    }
                    unsigned long long mb = __ballot(pred);
                    if (pred) {
                        int pos = cn2 + (int)__popcll(mb & ((1ull << lane) - 1ull));
                        if (pos < CANDCAP) { kn2d[wid][pos] = d; kn2i[wid][pos] = j; }
                    }
                    cn2 += (int)__popcll(mb);
                }
                if (cn2 > CANDCAP) cn2 = CANDCAP;
                for (int t = lane; t < cn2; t += 64) {
                    float d = kn2d[wid][t]; int j = kn2i[wid][t];
                    int rank = 0;
                    for (int u = 0; u < cn2; ++u) {
                        float du = kn2d[wid][u]; int iu = kn2i[wid][u];
                        rank += (du < d || (du == d && iu < j)) ? 1 : 0;
                    }
                    if (rank < KNN) {
                        float rx = (sx[j] - qx2) * INVR1;
                        float ry = (sy[j] - qy2) * INVR1;
                        float rz = (sz[j] - qz2) * INVR1;
#pragma unroll
                        for (int f = 0; f < 5; ++f) {
                            float h = fmaf(rx, rw1[f], fmaf(ry, rw1[5 + f], fmaf(rz, rw1[10 + f], rb1[f])));
                            fmx[f] = fmaxf(fmx[f], fmaxf(h, 0.0f));
                        }
                    }
                }
            }
#pragma unroll
            for (int f = 0; f < 5; ++f) {
                float mx = wave_fmax(fmx[f]);
                if (lane == 0) f1s[s][f] = mx;
            }
        }
    }
    __syncthreads();

    // ---- knn2 + MLP2 -> f2 (one wave per sample2) ----
    for (int s = wid; s < M2C; s += NW) {
        float qx2 = s2x[s], qy2 = s2y[s], qz2 = s2z[s];
        int cn = 0;
#pragma unroll
        for (int c = 0; c < 2; ++c) {
            int j = c * 64 + lane;
            float d = 0.0f; bool pred = false;
            if (j < M1C) {
                d = dist3(smpx[j], smpy[j], smpz[j], qx2, qy2, qz2);
                pred = (d <= R2SQ);
            }
            unsigned long long mb = __ballot(pred);
            if (pred) {
                int pos = cn + (int)__popcll(mb & ((1ull << lane) - 1ull));
                kn2d[wid][pos] = d; kn2i[wid][pos] = j;   // cn<=100<CANDCAP
            }
            cn += (int)__popcll(mb);
        }
        float hmx[25];
#pragma unroll
        for (int f = 0; f < 25; ++f) hmx[f] = -1e30f;
        for (int t = lane; t < cn; t += 64) {
            float d = kn2d[wid][t]; int j = kn2i[wid][t];
            bool valid = true;
            if (cn > KNN) {
                int rank = 0;
                for (int u = 0; u < cn; ++u) {
                    float du = kn2d[wid][u]; int iu = kn2i[wid][u];
                    rank += (du < d || (du == d && iu < j)) ? 1 : 0;
                }
                valid = rank < KNN;
            }
            if (valid) {
                float in8[8];
                in8[0] = smpx[j] - qx2; in8[1] = smpy[j] - qy2; in8[2] = smpz[j] - qz2;
#pragma unroll
                for (int f = 0; f < 5; ++f) in8[3 + f] = f1s[j][f];
#pragma unroll
                for (int f = 0; f < 25; ++f) {
                    float h = b2s[f];
#pragma unroll
                    for (int i = 0; i < 8; ++i) h = fmaf(in8[i], w2s[i * 25 + f], h);
                    hmx[f] = fmaxf(hmx[f], fmaxf(h, 0.0f));
                }
            }
        }
#pragma unroll
        for (int f = 0; f < 25; ++f) {
            float mx = wave_fmax(hmx[f]);
            if (lane == 0) f2s[s][f] = mx;
        }
    }
    __syncthreads();

    // ---- MLP3 + max-pool -> latent (45) ----
    if (wid == 0 && lane < 45) {
        float lm = -1e30f;
        for (int r = 0; r < M2C; ++r) {
            float h = b3s[lane];
            h = fmaf(s2x[r] * 0.5f, w3s[0 * 45 + lane], h);
            h = fmaf(s2y[r] * 0.5f, w3s[1 * 45 + lane], h);
            h = fmaf(s2z[r] * 0.5f, w3s[2 * 45 + lane], h);
#pragma unroll
            for (int i = 0; i < 25; ++i) h = fmaf(f2s[r][i], w3s[(3 + i) * 45 + lane], h);
            lm = fmaxf(lm, fmaxf(h, 0.0f));
        }
        latent[lane] = lm;
    }
    __syncthreads();

    // ---- decoder stage 1: latent @ D1 + bD1 -> (5, 28) ----
    for (int t = tid; t < 140; t += TPB) {
        float acc = bD1[t];
        for (int i = 0; i < 45; i++) acc = fmaf(latent[i], D1[i * 140 + t], acc);
        int r = t / 28, c = t % 28;
        if (c < 3) decv[r][c] = acc;
        else cfs[r][c - 3] = fmaxf(acc, 0.0f);
    }
    __syncthreads();

    // ---- decoder stage 2: cf @ D2 + bD2 -> (100, 8) ----
    for (int t = tid; t < 800; t += TPB) {
        int r = t / 160, c = t % 160;
        float acc = bD2[c];
        for (int i = 0; i < 25; i++) acc = fmaf(cfs[r][i], D2[i * 160 + c], acc);
        int g = r * 20 + c / 8, c8 = c % 8;
        if (c8 < 3) dec2s[g][c8] = acc;
        else cf2s[g][c8 - 3] = fmaxf(acc, 0.0f);
    }
    __syncthreads();

    // ---- decoder stage 3 + compose output ----
    float* outb = out + (size_t)b * (NPTS * 3);
    for (int t = tid; t < NPTS * 3; t += TPB) {
        int n = t / 3, c = t % 3;
        int g = n / 20;
        int m = n / 400;
        int r60 = (n % 20) * 3 + c;
        float acc = bD3[r60];
        for (int i = 0; i < 5; i++) acc = fmaf(cf2s[g][i], D3[i * 60 + r60], acc);
        // out = ((dec*R3 + dec2)*R2 + dec3)*R1, R2 = 1
        float val = ((decv[m][c] * 2.0f + dec2s[g][c]) + acc) * 0.3f;
        outb[t] = val;
    }
}

extern "C" void kernel_launch(void* const* d_in, const int* in_sizes, int n_in,
                              void* d_out, int out_size, void* d_ws, size_t ws_size,
                              hipStream_t stream) {
    const float* P   = (const float*)d_in[0];
    const float* W1  = (const float*)d_in[1];
    const float* b1  = (const float*)d_in[2];
    const float* W2  = (const float*)d_in[3];
    const float* b2  = (const float*)d_in[4];
    const float* W3  = (const float*)d_in[5];
    const float* b3  = (const float*)d_in[6];
    const float* D1  = (const float*)d_in[7];
    const float* bD1 = (const float*)d_in[8];
    const float* D2  = (const float*)d_in[9];
    const float* bD2 = (const float*)d_in[10];
    const float* D3  = (const float*)d_in[11];
    const float* bD3 = (const float*)d_in[12];
    float* out = (float*)d_out;

    int B = in_sizes[0] / (NPTS * 3);
    hipLaunchKernelGGL(pointnet_kernel, dim3(B), dim3(TPB), 0, stream,
                       P, W1, b1, W2, b2, W3, b3, D1, bD1, D2, bD2, D3, bD3, out);
}